// Round 5
// baseline (864.662 us; speedup 1.0000x reference)
//
#include <hip/hip_runtime.h>
#include <hip/hip_bf16.h>

#define NROWS 262144
#define CDIM  128
#define BN_EPS 1e-5f
#define GGRID 2048
#define SPB   (NROWS / 16 / GGRID)   // stripes (16 rows) per block

typedef __attribute__((ext_vector_type(8))) short bf16x8;
typedef __attribute__((ext_vector_type(4))) float f32x4;
#define LROW 136   // LDS row stride in shorts (128 data + 8 pad)

// round-to-nearest-even fp32 -> bf16 bits
static __device__ __forceinline__ unsigned int f2bf_rtn(float f) {
  unsigned int u = __float_as_uint(f);
  return (u + 0x7fffu + ((u >> 16) & 1u)) >> 16;
}
static __device__ __forceinline__ float bf2f(unsigned int b) {
  return __uint_as_float(b << 16);
}

// h = in @ W^T + bias.  NORM: in' = relu(in*scale+shift) first (in-place safe),
// with scale/shift computed from raw stats+gamma+beta in the prologue.
// A staged through LDS pre-split into bf16 hi/lo planes, double-buffered.
// Block = 256 thr (4 waves), wave w owns cols [32w,32w+32). 16-row stripes.
template <bool NORM>
__global__ void __launch_bounds__(256, 8)
gemm_bn(const float* __restrict__ in, const float* __restrict__ W,
        const float* __restrict__ bias,
        const float* __restrict__ stats_in,   // [256] sum|sumsq (NORM only)
        const float* __restrict__ gamma, const float* __restrict__ beta,
        float* __restrict__ hout, float* __restrict__ stats)
{
  __shared__ __align__(16) short lds[2][2][16][LROW];  // [buf][hi/lo][row][k]

  const int tid  = threadIdx.x;
  const int lane = tid & 63;
  const int wave = tid >> 6;
  const int l15  = lane & 15;
  const int lq   = lane >> 4;
  const int wcol = wave * 32;
  const int srow = tid >> 4;         // staging row 0..15
  const int sk0  = (tid & 15) * 8;   // staging k-chunk

  // ---- B fragments in registers for the whole kernel (hi/lo split) ----
  bf16x8 bh[2][4], bl[2][4];
#pragma unroll
  for (int jt = 0; jt < 2; ++jt) {
    const float* wrow = W + (wcol + jt * 16 + l15) * CDIM;
#pragma unroll
    for (int ks = 0; ks < 4; ++ks) {
      const int k0 = ks * 32 + lq * 8;
      f32x4 w0 = *(const f32x4*)(wrow + k0);
      f32x4 w1 = *(const f32x4*)(wrow + k0 + 4);
      float wv[8] = {w0.x,w0.y,w0.z,w0.w,w1.x,w1.y,w1.z,w1.w};
#pragma unroll
      for (int e = 0; e < 8; ++e) {
        unsigned int h = f2bf_rtn(wv[e]);
        bh[jt][ks][e] = (short)h;
        bl[jt][ks][e] = (short)f2bf_rtn(wv[e] - bf2f(h));
      }
    }
  }

  float scv[8], shv[8];
  if constexpr (NORM) {
    const float inv_n = 1.0f / (float)NROWS;
#pragma unroll
    for (int e = 0; e < 8; ++e) {
      const int c = sk0 + e;
      float m  = stats_in[c] * inv_n;
      float v  = stats_in[CDIM + c] * inv_n - m * m;
      float sc = gamma[c] * rsqrtf(v + BN_EPS);
      scv[e] = sc;
      shv[e] = beta[c] - m * sc;
    }
  }

  const float bias0 = bias[wcol + l15];
  const float bias1 = bias[wcol + 16 + l15];
  float s0 = 0.f, s1 = 0.f, q0 = 0.f, q1 = 0.f;

  const int row0 = blockIdx.x * (SPB * 16);

  auto cvt_write = [&](int buf, f32x4 g0, f32x4 g1) {
    float av[8] = {g0.x,g0.y,g0.z,g0.w,g1.x,g1.y,g1.z,g1.w};
    if constexpr (NORM) {
#pragma unroll
      for (int e = 0; e < 8; ++e)
        av[e] = fmaxf(av[e] * scv[e] + shv[e], 0.f);
    }
    bf16x8 hi, lo;
#pragma unroll
    for (int e = 0; e < 8; ++e) {
      unsigned int h = f2bf_rtn(av[e]);
      hi[e] = (short)h;
      lo[e] = (short)f2bf_rtn(av[e] - bf2f(h));
    }
    *(bf16x8*)&lds[buf][0][srow][sk0] = hi;
    *(bf16x8*)&lds[buf][1][srow][sk0] = lo;
  };

  // prologue: stage stripe 0
  {
    const float* ap = in + (size_t)(row0 + srow) * CDIM + sk0;
    f32x4 g0 = *(const f32x4*)ap;
    f32x4 g1 = *(const f32x4*)(ap + 4);
    cvt_write(0, g0, g1);
  }
  __syncthreads();

  for (int s = 0; s < SPB; ++s) {
    const int cur = s & 1;
    const int r0 = row0 + s * 16;

    // issue next-stripe global loads EARLY (latency hides under MFMA phase)
    f32x4 g0 = {0,0,0,0}, g1 = {0,0,0,0};
    const bool more = (s + 1 < SPB);   // block-uniform
    if (more) {
      const float* ap = in + (size_t)(r0 + 16 + srow) * CDIM + sk0;
      g0 = *(const f32x4*)ap;
      g1 = *(const f32x4*)(ap + 4);
    }

    // compute stripe s from lds[cur]
    f32x4 acc0 = {0.f,0.f,0.f,0.f};
    f32x4 acc1 = {0.f,0.f,0.f,0.f};
#pragma unroll
    for (int ks = 0; ks < 4; ++ks) {
      const int kc = ks * 32 + lq * 8;
      bf16x8 ah = *(const bf16x8*)&lds[cur][0][l15][kc];
      bf16x8 al = *(const bf16x8*)&lds[cur][1][l15][kc];
      acc0 = __builtin_amdgcn_mfma_f32_16x16x32_bf16(al, bh[0][ks], acc0, 0, 0, 0);
      acc0 = __builtin_amdgcn_mfma_f32_16x16x32_bf16(ah, bl[0][ks], acc0, 0, 0, 0);
      acc0 = __builtin_amdgcn_mfma_f32_16x16x32_bf16(ah, bh[0][ks], acc0, 0, 0, 0);
      acc1 = __builtin_amdgcn_mfma_f32_16x16x32_bf16(al, bh[1][ks], acc1, 0, 0, 0);
      acc1 = __builtin_amdgcn_mfma_f32_16x16x32_bf16(ah, bl[1][ks], acc1, 0, 0, 0);
      acc1 = __builtin_amdgcn_mfma_f32_16x16x32_bf16(ah, bh[1][ks], acc1, 0, 0, 0);
    }

    // convert + write next stripe into the buffer freed at last barrier
    if (more) cvt_write(cur ^ 1, g0, g1);
    __syncthreads();

    // store stripe s (post-barrier -> in-place safe)
    float* op = hout + (size_t)(r0 + lq * 4) * CDIM + wcol + l15;
#pragma unroll
    for (int r = 0; r < 4; ++r) {
      float h0 = acc0[r] + bias0;
      float h1 = acc1[r] + bias1;
      s0 += h0; q0 += h0 * h0;
      s1 += h1; q1 += h1 * h1;
      op[r * CDIM] = h0;
      op[r * CDIM + 16] = h1;
    }
  }

  // reduce quarters (lanes differing in bits 4,5 share a column)
  s0 += __shfl_xor(s0, 16); s0 += __shfl_xor(s0, 32);
  s1 += __shfl_xor(s1, 16); s1 += __shfl_xor(s1, 32);
  q0 += __shfl_xor(q0, 16); q0 += __shfl_xor(q0, 32);
  q1 += __shfl_xor(q1, 16); q1 += __shfl_xor(q1, 32);
  if (lane < 16) {
    atomicAdd(&stats[wcol + lane],             s0);
    atomicAdd(&stats[wcol + 16 + lane],        s1);
    atomicAdd(&stats[CDIM + wcol + lane],      q0);
    atomicAdd(&stats[CDIM + wcol + 16 + lane], q1);
  }
}

// out = relu(h2*sc+sh) + x, coeffs computed from stats2+g2+be2 per thread.
// 64 B/lane/iter, columns invariant across grid-stride iters.
__global__ void __launch_bounds__(256)
finalize(const f32x4* __restrict__ h2, const f32x4* __restrict__ xin,
         const float* __restrict__ stats, const float* __restrict__ gamma,
         const float* __restrict__ beta, f32x4* __restrict__ outp)
{
  const int tid0 = blockIdx.x * blockDim.x + threadIdx.x;
  const int c0 = (tid0 * 16) & (CDIM - 1);   // 16 consecutive cols, no wrap

  const float inv_n = 1.0f / (float)NROWS;
  float sc[16], sh[16];
#pragma unroll
  for (int e = 0; e < 16; ++e) {
    const int c = c0 + e;
    float m = stats[c] * inv_n;
    float v = stats[CDIM + c] * inv_n - m * m;
    float s = gamma[c] * rsqrtf(v + BN_EPS);
    sc[e] = s;
    sh[e] = beta[c] - m * s;
  }

  const int n4 = NROWS * CDIM / 4;
  const int stride = gridDim.x * blockDim.x * 4;   // mult of 32 f32x4 -> c0 fixed
  for (int i = tid0 * 4; i < n4; i += stride) {
    f32x4 h[4], xv[4], o[4];
#pragma unroll
    for (int u = 0; u < 4; ++u) {
      h[u]  = h2[i + u];
      xv[u] = __builtin_nontemporal_load(&xin[i + u]);
    }
#pragma unroll
    for (int u = 0; u < 4; ++u) {
      o[u].x = fmaxf(h[u].x * sc[u*4+0] + sh[u*4+0], 0.f) + xv[u].x;
      o[u].y = fmaxf(h[u].y * sc[u*4+1] + sh[u*4+1], 0.f) + xv[u].y;
      o[u].z = fmaxf(h[u].z * sc[u*4+2] + sh[u*4+2], 0.f) + xv[u].z;
      o[u].w = fmaxf(h[u].w * sc[u*4+3] + sh[u*4+3], 0.f) + xv[u].w;
    }
#pragma unroll
    for (int u = 0; u < 4; ++u)
      __builtin_nontemporal_store(o[u], &outp[i + u]);
  }
}

extern "C" void kernel_launch(void* const* d_in, const int* in_sizes, int n_in,
                              void* d_out, int out_size, void* d_ws, size_t ws_size,
                              hipStream_t stream) {
  (void)in_sizes; (void)n_in; (void)out_size; (void)ws_size;
  const float* x   = (const float*)d_in[0];
  const float* W1  = (const float*)d_in[1];
  const float* b1  = (const float*)d_in[2];
  const float* g1  = (const float*)d_in[3];
  const float* be1 = (const float*)d_in[4];
  const float* W2  = (const float*)d_in[5];
  const float* b2  = (const float*)d_in[6];
  const float* g2  = (const float*)d_in[7];
  const float* be2 = (const float*)d_in[8];

  float* hbuf   = (float*)d_out;          // h1 then h2, in place
  float* stats1 = (float*)d_ws;           // [256] sum|sumsq
  float* stats2 = stats1 + 256;           // [256]

  (void)hipMemsetAsync(d_ws, 0, 2048, stream);  // zero the stats accumulators

  gemm_bn<false><<<GGRID, 256, 0, stream>>>(x, W1, b1, nullptr, nullptr, nullptr,
                                            hbuf, stats1);
  gemm_bn<true><<<GGRID, 256, 0, stream>>>(hbuf, W2, b2, stats1, g1, be1,
                                           hbuf, stats2);
  finalize<<<2048, 256, 0, stream>>>((const f32x4*)hbuf, (const f32x4*)x,
                                     stats2, g2, be2, (f32x4*)d_out);
}

// Round 9
// 471.433 us; speedup vs baseline: 1.8341x; 1.8341x over previous
//
#include <hip/hip_runtime.h>
#include <hip/hip_bf16.h>

#define NROWS 262144
#define CDIM  128
#define BN_EPS 1e-5f
#define GGRID 2048
#define SPB   (NROWS / 16 / GGRID)   // stripes (16 rows) per block

typedef __attribute__((ext_vector_type(8))) short bf16x8;
typedef __attribute__((ext_vector_type(4))) float f32x4;
#define LROW 136   // LDS row stride in shorts (128 data + 8 pad)

// round-to-nearest-even fp32 -> bf16 bits
static __device__ __forceinline__ unsigned int f2bf_rtn(float f) {
  unsigned int u = __float_as_uint(f);
  return (u + 0x7fffu + ((u >> 16) & 1u)) >> 16;
}
static __device__ __forceinline__ float bf2f(unsigned int b) {
  return __uint_as_float(b << 16);
}

// h = in @ W^T + bias.  NORM: in' = relu(in*scale+shift) first (in-place safe),
// with scale/shift computed from raw stats+gamma+beta in the prologue.
// A staged through LDS pre-split into bf16 hi/lo planes, double-buffered.
// Block = 256 thr (4 waves), wave w owns cols [32w,32w+32). 16-row stripes.
// NOTE: launch_bounds (256,4) on purpose — (256,8) forced VGPR=32 and spilled
// the 64-VGPR weight fragments to scratch (round-5: FETCH 86->697 MB, 3x slower).
template <bool NORM>
__global__ void __launch_bounds__(256, 4)
gemm_bn(const float* __restrict__ in, const float* __restrict__ W,
        const float* __restrict__ bias,
        const float* __restrict__ stats_in,   // [256] sum|sumsq (NORM only)
        const float* __restrict__ gamma, const float* __restrict__ beta,
        float* __restrict__ hout, float* __restrict__ stats)
{
  __shared__ __align__(16) short lds[2][2][16][LROW];  // [buf][hi/lo][row][k]

  const int tid  = threadIdx.x;
  const int lane = tid & 63;
  const int wave = tid >> 6;
  const int l15  = lane & 15;
  const int lq   = lane >> 4;
  const int wcol = wave * 32;
  const int srow = tid >> 4;         // staging row 0..15
  const int sk0  = (tid & 15) * 8;   // staging k-chunk

  // ---- B fragments in registers for the whole kernel (hi/lo split) ----
  bf16x8 bh[2][4], bl[2][4];
#pragma unroll
  for (int jt = 0; jt < 2; ++jt) {
    const float* wrow = W + (wcol + jt * 16 + l15) * CDIM;
#pragma unroll
    for (int ks = 0; ks < 4; ++ks) {
      const int k0 = ks * 32 + lq * 8;
      f32x4 w0 = *(const f32x4*)(wrow + k0);
      f32x4 w1 = *(const f32x4*)(wrow + k0 + 4);
      float wv[8] = {w0.x,w0.y,w0.z,w0.w,w1.x,w1.y,w1.z,w1.w};
#pragma unroll
      for (int e = 0; e < 8; ++e) {
        unsigned int h = f2bf_rtn(wv[e]);
        bh[jt][ks][e] = (short)h;
        bl[jt][ks][e] = (short)f2bf_rtn(wv[e] - bf2f(h));
      }
    }
  }

  float scv[8], shv[8];
  if constexpr (NORM) {
    const float inv_n = 1.0f / (float)NROWS;
#pragma unroll
    for (int e = 0; e < 8; ++e) {
      const int c = sk0 + e;
      float m  = stats_in[c] * inv_n;
      float v  = stats_in[CDIM + c] * inv_n - m * m;
      float sc = gamma[c] * rsqrtf(v + BN_EPS);
      scv[e] = sc;
      shv[e] = beta[c] - m * sc;
    }
  }

  const float bias0 = bias[wcol + l15];
  const float bias1 = bias[wcol + 16 + l15];
  float s0 = 0.f, s1 = 0.f, q0 = 0.f, q1 = 0.f;

  const int row0 = blockIdx.x * (SPB * 16);

  auto cvt_write = [&](int buf, f32x4 g0, f32x4 g1) {
    float av[8] = {g0.x,g0.y,g0.z,g0.w,g1.x,g1.y,g1.z,g1.w};
    if constexpr (NORM) {
#pragma unroll
      for (int e = 0; e < 8; ++e)
        av[e] = fmaxf(av[e] * scv[e] + shv[e], 0.f);
    }
    bf16x8 hi, lo;
#pragma unroll
    for (int e = 0; e < 8; ++e) {
      unsigned int h = f2bf_rtn(av[e]);
      hi[e] = (short)h;
      lo[e] = (short)f2bf_rtn(av[e] - bf2f(h));
    }
    *(bf16x8*)&lds[buf][0][srow][sk0] = hi;
    *(bf16x8*)&lds[buf][1][srow][sk0] = lo;
  };

  // prologue: stage stripe 0
  {
    const float* ap = in + (size_t)(row0 + srow) * CDIM + sk0;
    f32x4 g0 = *(const f32x4*)ap;
    f32x4 g1 = *(const f32x4*)(ap + 4);
    cvt_write(0, g0, g1);
  }
  __syncthreads();

  for (int s = 0; s < SPB; ++s) {
    const int cur = s & 1;
    const int r0 = row0 + s * 16;

    // issue next-stripe global loads EARLY (latency hides under MFMA phase)
    f32x4 g0 = {0,0,0,0}, g1 = {0,0,0,0};
    const bool more = (s + 1 < SPB);   // block-uniform
    if (more) {
      const float* ap = in + (size_t)(r0 + 16 + srow) * CDIM + sk0;
      g0 = *(const f32x4*)ap;
      g1 = *(const f32x4*)(ap + 4);
    }

    // compute stripe s from lds[cur]
    f32x4 acc0 = {0.f,0.f,0.f,0.f};
    f32x4 acc1 = {0.f,0.f,0.f,0.f};
#pragma unroll
    for (int ks = 0; ks < 4; ++ks) {
      const int kc = ks * 32 + lq * 8;
      bf16x8 ah = *(const bf16x8*)&lds[cur][0][l15][kc];
      bf16x8 al = *(const bf16x8*)&lds[cur][1][l15][kc];
      acc0 = __builtin_amdgcn_mfma_f32_16x16x32_bf16(al, bh[0][ks], acc0, 0, 0, 0);
      acc0 = __builtin_amdgcn_mfma_f32_16x16x32_bf16(ah, bl[0][ks], acc0, 0, 0, 0);
      acc0 = __builtin_amdgcn_mfma_f32_16x16x32_bf16(ah, bh[0][ks], acc0, 0, 0, 0);
      acc1 = __builtin_amdgcn_mfma_f32_16x16x32_bf16(al, bh[1][ks], acc1, 0, 0, 0);
      acc1 = __builtin_amdgcn_mfma_f32_16x16x32_bf16(ah, bl[1][ks], acc1, 0, 0, 0);
      acc1 = __builtin_amdgcn_mfma_f32_16x16x32_bf16(ah, bh[1][ks], acc1, 0, 0, 0);
    }

    // convert + write next stripe into the buffer freed at last barrier
    if (more) cvt_write(cur ^ 1, g0, g1);
    __syncthreads();

    // store stripe s (post-barrier -> in-place safe)
    float* op = hout + (size_t)(r0 + lq * 4) * CDIM + wcol + l15;
#pragma unroll
    for (int r = 0; r < 4; ++r) {
      float h0 = acc0[r] + bias0;
      float h1 = acc1[r] + bias1;
      s0 += h0; q0 += h0 * h0;
      s1 += h1; q1 += h1 * h1;
      op[r * CDIM] = h0;
      op[r * CDIM + 16] = h1;
    }
  }

  // reduce quarters (lanes differing in bits 4,5 share a column)
  s0 += __shfl_xor(s0, 16); s0 += __shfl_xor(s0, 32);
  s1 += __shfl_xor(s1, 16); s1 += __shfl_xor(s1, 32);
  q0 += __shfl_xor(q0, 16); q0 += __shfl_xor(q0, 32);
  q1 += __shfl_xor(q1, 16); q1 += __shfl_xor(q1, 32);
  if (lane < 16) {
    atomicAdd(&stats[wcol + lane],             s0);
    atomicAdd(&stats[wcol + 16 + lane],        s1);
    atomicAdd(&stats[CDIM + wcol + lane],      q0);
    atomicAdd(&stats[CDIM + wcol + 16 + lane], q1);
  }
}

// out = relu(h2*sc+sh) + x, coeffs computed from stats2+g2+be2 per thread.
// Lane-contiguous accesses (16 B/lane/instr, 1 KB/wave), 4 streams per thread
// at grid-stride offsets; stride*4 cols == 0 mod 128 -> coeffs loop-invariant.
__global__ void __launch_bounds__(256)
finalize(const f32x4* __restrict__ h2, const f32x4* __restrict__ xin,
         const float* __restrict__ stats, const float* __restrict__ gamma,
         const float* __restrict__ beta, f32x4* __restrict__ outp)
{
  const int tid0 = blockIdx.x * blockDim.x + threadIdx.x;  // f32x4 index
  const int c0 = (tid0 * 4) & (CDIM - 1);                  // 4 consecutive cols

  const float inv_n = 1.0f / (float)NROWS;
  float sc[4], sh[4];
#pragma unroll
  for (int e = 0; e < 4; ++e) {
    const int c = c0 + e;
    float m = stats[c] * inv_n;
    float v = stats[CDIM + c] * inv_n - m * m;
    float s = gamma[c] * rsqrtf(v + BN_EPS);
    sc[e] = s;
    sh[e] = beta[c] - m * s;
  }

  const int n4 = NROWS * CDIM / 4;            // 8388608 f32x4
  const int GR = gridDim.x * blockDim.x;      // 524288 (grid 2048): GR*4 % 128 == 0
  for (int base = tid0; base < n4; base += GR * 4) {
    f32x4 h[4], xv[4], o[4];
#pragma unroll
    for (int u = 0; u < 4; ++u) {
      h[u]  = h2[base + u * GR];
      xv[u] = __builtin_nontemporal_load(&xin[base + u * GR]);
    }
#pragma unroll
    for (int u = 0; u < 4; ++u) {
      o[u].x = fmaxf(h[u].x * sc[0] + sh[0], 0.f) + xv[u].x;
      o[u].y = fmaxf(h[u].y * sc[1] + sh[1], 0.f) + xv[u].y;
      o[u].z = fmaxf(h[u].z * sc[2] + sh[2], 0.f) + xv[u].z;
      o[u].w = fmaxf(h[u].w * sc[3] + sh[3], 0.f) + xv[u].w;
    }
#pragma unroll
    for (int u = 0; u < 4; ++u)
      __builtin_nontemporal_store(o[u], &outp[base + u * GR]);
  }
}

extern "C" void kernel_launch(void* const* d_in, const int* in_sizes, int n_in,
                              void* d_out, int out_size, void* d_ws, size_t ws_size,
                              hipStream_t stream) {
  (void)in_sizes; (void)n_in; (void)out_size; (void)ws_size;
  const float* x   = (const float*)d_in[0];
  const float* W1  = (const float*)d_in[1];
  const float* b1  = (const float*)d_in[2];
  const float* g1  = (const float*)d_in[3];
  const float* be1 = (const float*)d_in[4];
  const float* W2  = (const float*)d_in[5];
  const float* b2  = (const float*)d_in[6];
  const float* g2  = (const float*)d_in[7];
  const float* be2 = (const float*)d_in[8];

  float* hbuf   = (float*)d_out;          // h1 then h2, in place
  float* stats1 = (float*)d_ws;           // [256] sum|sumsq
  float* stats2 = stats1 + 256;           // [256]

  (void)hipMemsetAsync(d_ws, 0, 2048, stream);  // zero the stats accumulators

  gemm_bn<false><<<GGRID, 256, 0, stream>>>(x, W1, b1, nullptr, nullptr, nullptr,
                                            hbuf, stats1);
  gemm_bn<true><<<GGRID, 256, 0, stream>>>(hbuf, W2, b2, stats1, g1, be1,
                                           hbuf, stats2);
  finalize<<<2048, 256, 0, stream>>>((const f32x4*)hbuf, (const f32x4*)x,
                                     stats2, g2, be2, (f32x4*)d_out);
}

// Round 11
// 456.659 us; speedup vs baseline: 1.8935x; 1.0324x over previous
//
#include <hip/hip_runtime.h>
#include <hip/hip_bf16.h>

#define NROWS 262144
#define CDIM  128
#define BN_EPS 1e-5f
#define GGRID 1024
#define SROWS 32                       // rows per stripe
#define SPB   (NROWS / SROWS / GGRID)  // 8 stripes per block

typedef __attribute__((ext_vector_type(8))) short bf16x8;
typedef __attribute__((ext_vector_type(4))) float f32x4;
#define LROW 136   // LDS row stride in shorts (128 data + 8 pad)

static __device__ __forceinline__ unsigned int f2bf_rtn(float f) {
  unsigned int u = __float_as_uint(f);
  return (u + 0x7fffu + ((u >> 16) & 1u)) >> 16;
}
static __device__ __forceinline__ float bf2f(unsigned int b) {
  return __uint_as_float(b << 16);
}

// h = in @ W^T + bias.  NORM: in' = relu(in*scale+shift) first (in-place safe).
// A staged through LDS pre-split into bf16 hi/lo planes, double-buffered,
// 32-row stripes (4x16B loads/thread in flight -> ~16KB/block outstanding).
// Per-column sum/sumsq partials stored per block (coalesced), no atomics.
template <bool NORM>
__global__ void __launch_bounds__(256, 4)
gemm_bn(const float* __restrict__ in, const float* __restrict__ W,
        const float* __restrict__ bias,
        const float* __restrict__ scsh_in,   // [256] scale|shift (NORM only)
        float* __restrict__ hout, float* __restrict__ part)
{
  __shared__ __align__(16) short lds[2][2][SROWS][LROW];  // 34816 B

  const int tid  = threadIdx.x;
  const int lane = tid & 63;
  const int wave = tid >> 6;
  const int l15  = lane & 15;
  const int lq   = lane >> 4;
  const int wcol = wave * 32;
  const int srow = tid >> 4;         // staging row 0..15 (and +16)
  const int sk0  = (tid & 15) * 8;   // staging k-chunk

  // ---- B fragments in registers (hi/lo split): 64 VGPRs ----
  bf16x8 bh[2][4], bl[2][4];
#pragma unroll
  for (int jt = 0; jt < 2; ++jt) {
    const float* wrow = W + (wcol + jt * 16 + l15) * CDIM;
#pragma unroll
    for (int ks = 0; ks < 4; ++ks) {
      const int k0 = ks * 32 + lq * 8;
      f32x4 w0 = *(const f32x4*)(wrow + k0);
      f32x4 w1 = *(const f32x4*)(wrow + k0 + 4);
      float wv[8] = {w0.x,w0.y,w0.z,w0.w,w1.x,w1.y,w1.z,w1.w};
#pragma unroll
      for (int e = 0; e < 8; ++e) {
        unsigned int h = f2bf_rtn(wv[e]);
        bh[jt][ks][e] = (short)h;
        bl[jt][ks][e] = (short)f2bf_rtn(wv[e] - bf2f(h));
      }
    }
  }

  float scv[8], shv[8];
  if constexpr (NORM) {
#pragma unroll
    for (int e = 0; e < 8; ++e) {
      scv[e] = scsh_in[sk0 + e];
      shv[e] = scsh_in[CDIM + sk0 + e];
    }
  }

  const float bias0 = bias[wcol + l15];
  const float bias1 = bias[wcol + 16 + l15];
  float s0 = 0.f, s1 = 0.f, q0 = 0.f, q1 = 0.f;

  const int row0 = blockIdx.x * (SPB * SROWS);

  auto cvt_write = [&](int buf, int lrow, f32x4 g0, f32x4 g1) {
    float av[8] = {g0.x,g0.y,g0.z,g0.w,g1.x,g1.y,g1.z,g1.w};
    if constexpr (NORM) {
#pragma unroll
      for (int e = 0; e < 8; ++e)
        av[e] = fmaxf(av[e] * scv[e] + shv[e], 0.f);
    }
    bf16x8 hi, lo;
#pragma unroll
    for (int e = 0; e < 8; ++e) {
      unsigned int h = f2bf_rtn(av[e]);
      hi[e] = (short)h;
      lo[e] = (short)f2bf_rtn(av[e] - bf2f(h));
    }
    *(bf16x8*)&lds[buf][0][lrow][sk0] = hi;
    *(bf16x8*)&lds[buf][1][lrow][sk0] = lo;
  };

  // prologue: stage stripe 0 (rows srow and srow+16)
  {
    const float* a0 = in + (size_t)(row0 + srow) * CDIM + sk0;
    const float* a1 = in + (size_t)(row0 + 16 + srow) * CDIM + sk0;
    f32x4 g0 = *(const f32x4*)a0, g1 = *(const f32x4*)(a0 + 4);
    f32x4 g2 = *(const f32x4*)a1, g3 = *(const f32x4*)(a1 + 4);
    cvt_write(0, srow, g0, g1);
    cvt_write(0, srow + 16, g2, g3);
  }
  __syncthreads();

  for (int s = 0; s < SPB; ++s) {
    const int cur = s & 1;
    const int r0 = row0 + s * SROWS;

    // issue next-stripe loads EARLY: 4x16B/thread outstanding
    f32x4 g0 = {0,0,0,0}, g1 = {0,0,0,0}, g2 = {0,0,0,0}, g3 = {0,0,0,0};
    const bool more = (s + 1 < SPB);   // block-uniform
    if (more) {
      const float* a0 = in + (size_t)(r0 + SROWS + srow) * CDIM + sk0;
      const float* a1 = in + (size_t)(r0 + SROWS + 16 + srow) * CDIM + sk0;
      g0 = *(const f32x4*)a0; g1 = *(const f32x4*)(a0 + 4);
      g2 = *(const f32x4*)a1; g3 = *(const f32x4*)(a1 + 4);
    }

    // compute stripe s (two 16-row sub-tiles) from lds[cur]
    f32x4 acc[2][2];
#pragma unroll
    for (int st = 0; st < 2; ++st)
#pragma unroll
      for (int jt = 0; jt < 2; ++jt)
        acc[st][jt] = (f32x4){0.f,0.f,0.f,0.f};

#pragma unroll
    for (int st = 0; st < 2; ++st) {
#pragma unroll
      for (int ks = 0; ks < 4; ++ks) {
        const int kc = ks * 32 + lq * 8;
        bf16x8 ah = *(const bf16x8*)&lds[cur][0][st * 16 + l15][kc];
        bf16x8 al = *(const bf16x8*)&lds[cur][1][st * 16 + l15][kc];
        acc[st][0] = __builtin_amdgcn_mfma_f32_16x16x32_bf16(al, bh[0][ks], acc[st][0], 0, 0, 0);
        acc[st][0] = __builtin_amdgcn_mfma_f32_16x16x32_bf16(ah, bl[0][ks], acc[st][0], 0, 0, 0);
        acc[st][0] = __builtin_amdgcn_mfma_f32_16x16x32_bf16(ah, bh[0][ks], acc[st][0], 0, 0, 0);
        acc[st][1] = __builtin_amdgcn_mfma_f32_16x16x32_bf16(al, bh[1][ks], acc[st][1], 0, 0, 0);
        acc[st][1] = __builtin_amdgcn_mfma_f32_16x16x32_bf16(ah, bl[1][ks], acc[st][1], 0, 0, 0);
        acc[st][1] = __builtin_amdgcn_mfma_f32_16x16x32_bf16(ah, bh[1][ks], acc[st][1], 0, 0, 0);
      }
    }

    // convert + write next stripe into the freed buffer
    if (more) {
      cvt_write(cur ^ 1, srow, g0, g1);
      cvt_write(cur ^ 1, srow + 16, g2, g3);
    }
    __syncthreads();

    // store stripe s (post-barrier -> in-place safe)
#pragma unroll
    for (int st = 0; st < 2; ++st) {
      float* op = hout + (size_t)(r0 + st * 16 + lq * 4) * CDIM + wcol + l15;
#pragma unroll
      for (int r = 0; r < 4; ++r) {
        float h0 = acc[st][0][r] + bias0;
        float h1 = acc[st][1][r] + bias1;
        s0 += h0; q0 += h0 * h0;
        s1 += h1; q1 += h1 * h1;
        op[r * CDIM] = h0;
        op[r * CDIM + 16] = h1;
      }
    }
  }

  // reduce quarters; store per-block partials (coalesced, no atomics)
  s0 += __shfl_xor(s0, 16); s0 += __shfl_xor(s0, 32);
  s1 += __shfl_xor(s1, 16); s1 += __shfl_xor(s1, 32);
  q0 += __shfl_xor(q0, 16); q0 += __shfl_xor(q0, 32);
  q1 += __shfl_xor(q1, 16); q1 += __shfl_xor(q1, 32);
  float* pb = part + (size_t)blockIdx.x * 256;
  if (lane < 16) {
    pb[wcol + lane]              = s0;
    pb[wcol + 16 + lane]         = s1;
    pb[CDIM + wcol + lane]       = q0;
    pb[CDIM + wcol + 16 + lane]  = q1;
  }
}

// Reduce per-block partials -> scale|shift per column. Grid = 128 (1 col/block).
__global__ void __launch_bounds__(256)
bn_stats(const float* __restrict__ part, const float* __restrict__ gamma,
         const float* __restrict__ beta, float* __restrict__ scsh)
{
  const int c = blockIdx.x;
  const int t = threadIdx.x;
  float s = 0.f, q = 0.f;
  for (int b = t; b < GGRID; b += 256) {
    s += part[(size_t)b * 256 + c];
    q += part[(size_t)b * 256 + CDIM + c];
  }
  __shared__ float rs[256], rq[256];
  rs[t] = s; rq[t] = q;
  __syncthreads();
#pragma unroll
  for (int off = 128; off >= 1; off >>= 1) {
    if (t < off) { rs[t] += rs[t + off]; rq[t] += rq[t + off]; }
    __syncthreads();
  }
  if (t == 0) {
    const float inv_n = 1.0f / (float)NROWS;
    float m  = rs[0] * inv_n;
    float v  = rq[0] * inv_n - m * m;
    float sc = gamma[c] * rsqrtf(v + BN_EPS);
    scsh[c]        = sc;
    scsh[CDIM + c] = beta[c] - m * sc;
  }
}

// out = relu(h2*sc+sh) + x. Lane-contiguous, 4 grid-stride streams/thread.
__global__ void __launch_bounds__(256)
finalize(const f32x4* __restrict__ h2, const f32x4* __restrict__ xin,
         const float* __restrict__ scsh, f32x4* __restrict__ outp)
{
  const int tid0 = blockIdx.x * blockDim.x + threadIdx.x;  // f32x4 index
  const int c0 = (tid0 * 4) & (CDIM - 1);                  // 4 consecutive cols

  float sc[4], sh[4];
#pragma unroll
  for (int e = 0; e < 4; ++e) {
    sc[e] = scsh[c0 + e];
    sh[e] = scsh[CDIM + c0 + e];
  }

  const int n4 = NROWS * CDIM / 4;
  const int GR = gridDim.x * blockDim.x;   // grid 4096: GR*4 % 128 == 0
  for (int base = tid0; base < n4; base += GR * 4) {
    f32x4 h[4], xv[4], o[4];
#pragma unroll
    for (int u = 0; u < 4; ++u) {
      h[u]  = h2[base + u * GR];
      xv[u] = __builtin_nontemporal_load(&xin[base + u * GR]);
    }
#pragma unroll
    for (int u = 0; u < 4; ++u) {
      o[u].x = fmaxf(h[u].x * sc[0] + sh[0], 0.f) + xv[u].x;
      o[u].y = fmaxf(h[u].y * sc[1] + sh[1], 0.f) + xv[u].y;
      o[u].z = fmaxf(h[u].z * sc[2] + sh[2], 0.f) + xv[u].z;
      o[u].w = fmaxf(h[u].w * sc[3] + sh[3], 0.f) + xv[u].w;
    }
#pragma unroll
    for (int u = 0; u < 4; ++u)
      __builtin_nontemporal_store(o[u], &outp[base + u * GR]);
  }
}

extern "C" void kernel_launch(void* const* d_in, const int* in_sizes, int n_in,
                              void* d_out, int out_size, void* d_ws, size_t ws_size,
                              hipStream_t stream) {
  (void)in_sizes; (void)n_in; (void)out_size; (void)ws_size;
  const float* x   = (const float*)d_in[0];
  const float* W1  = (const float*)d_in[1];
  const float* b1  = (const float*)d_in[2];
  const float* g1  = (const float*)d_in[3];
  const float* be1 = (const float*)d_in[4];
  const float* W2  = (const float*)d_in[5];
  const float* b2  = (const float*)d_in[6];
  const float* g2  = (const float*)d_in[7];
  const float* be2 = (const float*)d_in[8];

  float* hbuf  = (float*)d_out;                 // h1 then h2, in place
  float* part1 = (float*)d_ws;                  // [GGRID][256]
  float* part2 = part1 + (size_t)GGRID * 256;   // [GGRID][256]
  float* scsh1 = part2 + (size_t)GGRID * 256;   // [256]
  float* scsh2 = scsh1 + 256;                   // [256]
  // all ws regions fully written before read -> no memset needed

  gemm_bn<false><<<GGRID, 256, 0, stream>>>(x, W1, b1, nullptr, hbuf, part1);
  bn_stats<<<CDIM, 256, 0, stream>>>(part1, g1, be1, scsh1);
  gemm_bn<true><<<GGRID, 256, 0, stream>>>(hbuf, W2, b2, scsh1, hbuf, part2);
  bn_stats<<<CDIM, 256, 0, stream>>>(part2, g2, be2, scsh2);
  finalize<<<4096, 256, 0, stream>>>((const f32x4*)hbuf, (const f32x4*)x,
                                     scsh2, (f32x4*)d_out);
}